// Round 1
// baseline (463.194 us; speedup 1.0000x reference)
//
#include <hip/hip_runtime.h>

#define BS   16
#define NMEM 256
#define NQ   63
#define T    64          // NQ + 1
#define D    512
#define H    512
#define G4   2048        // 4*H

#define K2C  2.885390081777927f   // 2*log2(e)

typedef __attribute__((ext_vector_type(8))) short short8;
typedef __attribute__((ext_vector_type(4))) float float4v;

// ---------------- workspace layout (float offsets) ----------------
enum : size_t {
    OFF_XW  = 0,                            // [T][BS][G4]
    OFF_YS  = OFF_XW  + (size_t)T*BS*G4,    // [T+1][BS][H]  (fp32, b-major, for q-gemm)
    OFF_HB  = OFF_YS  + (size_t)(T+1)*BS*H, // [T+1][2][8192] bf16 hi/lo
    OFF_AF  = OFF_HB  + (size_t)(T+1)*BS*H, // [BS][NMEM][H]
    OFF_Q   = OFF_AF  + (size_t)BS*NMEM*H,  // [T][BS][H]
    OFF_X   = OFF_Q   + (size_t)T*BS*H,     // [T][BS][D]
    OFF_B   = OFF_X   + (size_t)T*BS*D,     // [G4]
    OFF_BAR = OFF_B   + (size_t)G4,         // 512 ints: 32 flags, stride 16
};

__device__ inline unsigned short bf16_rn(float x) {
    union { float f; unsigned u; } a; a.f = x;
    unsigned r = a.u + 0x7FFFu + ((a.u >> 16) & 1u);
    return (unsigned short)(r >> 16);
}
__device__ inline float bf16_to_f(unsigned short s) {
    union { float f; unsigned u; } a; a.u = ((unsigned)s) << 16;
    return a.f;
}

// ---------------- prep: build x, bias, hbuf[0] ----------------
__global__ void prep(const float* __restrict__ lstm_in, const float* __restrict__ init_h,
                     const float* __restrict__ init_i,
                     const float* __restrict__ b_ih, const float* __restrict__ b_hh,
                     float* __restrict__ xbuf, float* __restrict__ biasbuf,
                     unsigned short* __restrict__ hb0)
{
    int i = blockIdx.x * blockDim.x + threadIdx.x;
    const int NX = T*BS*D;
    if (i < NX) {
        int d = i & 511; int r = i >> 9; int t = r >> 4; int b = r & 15;
        float v = (t == 0) ? init_i[d] : lstm_in[((size_t)(b*NQ) + (t-1))*D + d];
        __builtin_nontemporal_store(v, xbuf + i);
    } else if (i < NX + G4) {
        int j = i - NX; biasbuf[j] = b_ih[j] + b_hh[j];
    } else if (i < NX + G4 + 8192) {
        int e = i - (NX + G4);
        int iw = e & 7;
        int k = ((e >> 3) >> 4) * 8 + iw;
        float h0 = init_h[k];
        unsigned short hi = bf16_rn(h0);
        unsigned short lo = bf16_rn(h0 - bf16_to_f(hi));
        hb0[e] = hi;
        hb0[8192 + e] = lo;
    }
}

// ---------------- split-bf16 MFMA GEMM unit ----------------
// 256 threads compute a 64x64 C tile of A[M,K] @ op(B), fp32 in/out.
// BT=true: B is [N,K] (C = A*B^T). BT=false: B is [K,N].
// C = Ah*Bh + Al*Bh + Ah*Bl (split-bf16, ~2^-16 relative).
template<bool BT>
__device__ inline void gemm_unit(const float* __restrict__ A, const float* __restrict__ B,
                                 float* __restrict__ C, const float* __restrict__ bias,
                                 int N, int K, int tm, int tn, int t2)
{
    const int w = t2 >> 6, lane = t2 & 63;
    const int quad = lane >> 4, l15 = lane & 15;
    const int am = tm + w*16 + l15;
    float4v acch[4] = {{0,0,0,0},{0,0,0,0},{0,0,0,0},{0,0,0,0}};
    float4v accl[4] = {{0,0,0,0},{0,0,0,0},{0,0,0,0},{0,0,0,0}};
    for (int k0 = 0; k0 < K; k0 += 32) {
        const float* ap = A + (size_t)am*K + k0 + quad*8;
        float4 a0 = *(const float4*)ap, a1 = *(const float4*)(ap+4);
        float av[8] = {a0.x,a0.y,a0.z,a0.w,a1.x,a1.y,a1.z,a1.w};
        short8 ah, al;
#pragma unroll
        for (int i = 0; i < 8; ++i) {
            unsigned short hi = bf16_rn(av[i]);
            ah[i] = (short)hi; al[i] = (short)bf16_rn(av[i] - bf16_to_f(hi));
        }
#pragma unroll
        for (int ni = 0; ni < 4; ++ni) {
            const int n = tn + ni*16 + l15;
            float bv[8];
            if (BT) {
                const float* bp = B + (size_t)n*K + k0 + quad*8;
                float4 b0 = *(const float4*)bp, b1 = *(const float4*)(bp+4);
                bv[0]=b0.x; bv[1]=b0.y; bv[2]=b0.z; bv[3]=b0.w;
                bv[4]=b1.x; bv[5]=b1.y; bv[6]=b1.z; bv[7]=b1.w;
            } else {
                const float* bp = B + (size_t)(k0 + quad*8)*N + n;
#pragma unroll
                for (int i = 0; i < 8; ++i) bv[i] = bp[(size_t)i*N];
            }
            short8 bh, bl;
#pragma unroll
            for (int i = 0; i < 8; ++i) {
                unsigned short hi = bf16_rn(bv[i]);
                bh[i] = (short)hi; bl[i] = (short)bf16_rn(bv[i] - bf16_to_f(hi));
            }
            acch[ni] = __builtin_amdgcn_mfma_f32_16x16x32_bf16(ah, bh, acch[ni], 0, 0, 0);
            accl[ni] = __builtin_amdgcn_mfma_f32_16x16x32_bf16(al, bh, accl[ni], 0, 0, 0);
            accl[ni] = __builtin_amdgcn_mfma_f32_16x16x32_bf16(ah, bl, accl[ni], 0, 0, 0);
        }
    }
#pragma unroll
    for (int ni = 0; ni < 4; ++ni) {
        const int n = tn + ni*16 + l15;
        float bb = bias ? bias[n] : 0.f;
        float4v r = acch[ni] + accl[ni];
#pragma unroll
        for (int j = 0; j < 4; ++j) {
            int row = tm + w*16 + quad*4 + j;
            __builtin_nontemporal_store(r[j] + bb, C + (size_t)row*N + n);
        }
    }
}

template<bool BT>
__global__ __launch_bounds__(256) void gemm_mfma(const float* __restrict__ A,
                                                 const float* __restrict__ B,
                                                 float* __restrict__ C,
                                                 const float* __restrict__ bias,
                                                 int N, int K)
{
    gemm_unit<BT>(A, B, C, bias, N, K, blockIdx.y*64, blockIdx.x*64, threadIdx.x);
}

// ---------------- persistent LSTM (blocks 0-31) + fused af GEMM (blocks 32-287) ----
// lstm: block jt owns hidden j-tile of 16 x 4 gates; 8 waves = (gate, k-half);
// weights as bf16 hi/lo B-fragments in VGPRs; h exchanged via L3 (bf16 hi/lo);
// barrier v4: per-block release flags + wave-parallel poll + one acquire fence.
// af: blocks 32-287 each run two independent 64x64 gemm_unit tiles of ks@wm.
__global__ __launch_bounds__(512, 2) void lstm_af(
    const float* __restrict__ xW,        // [T][BS][G4]
    const float* __restrict__ w_hh,      // [G4][H]
    const float* __restrict__ init_c,    // [H]
    const float* __restrict__ ks,        // [BS*NMEM][D]
    const float* __restrict__ wm,        // [D][H]
    float* __restrict__ ys,              // [T+1][BS][H]
    unsigned short* __restrict__ hbuf,   // [T+1][2][8192]
    float* __restrict__ af,              // [BS*NMEM][H]
    int* __restrict__ flags)             // 32 flags, stride 16 ints
{
    const int tid = threadIdx.x;

    if (blockIdx.x >= 32) {
        // ---------- fused af = ks @ wm (split-bf16 MFMA, no LDS, no barriers) ------
        const int u = tid >> 8;                    // two 256-thr units per block
        const int tau = (blockIdx.x - 32)*2 + u;   // 0..511 tiles: M=4096/64 x N=512/64
        gemm_unit<false>(ks, wm, af, nullptr, H, D, (tau >> 3)*64, (tau & 7)*64, tid & 255);
        return;
    }

    // ---------- LSTM recurrence ----------
    __shared__ float smem[3328];
    float* part = smem;              // [8][64][4]
    float* cst  = smem + 2048;       // [16][16]
    float* xwb  = smem + 2304;       // [4][16][16]  (gate, b, j16) staged xW[t]

    const int jt    = blockIdx.x;
    const int w     = tid >> 6;
    const int g     = w >> 1;
    const int khalf = w & 1;
    const int lane  = tid & 63;
    const int quad  = lane >> 4;
    const int l15   = lane & 15;

    // one-time weight preload -> bf16 hi/lo B-fragments in VGPRs
    short8 bh[8], bl[8];
    {
        const int row = g*512 + jt*16 + l15;
        const float* wr = w_hh + (size_t)row*H + khalf*256 + quad*8;
#pragma unroll
        for (int kt = 0; kt < 8; ++kt) {
            const float* wp = wr + kt*32;
#pragma unroll
            for (int i = 0; i < 8; ++i) {
                float v = wp[i];
                unsigned short hi = bf16_rn(v);
                bh[kt][i] = (short)hi;
                bl[kt][i] = (short)bf16_rn(v - bf16_to_f(hi));
            }
        }
    }

    const int b2 = tid >> 4, j16 = tid & 15;       // finalize mapping (tid<256)
    if (tid < 256) cst[b2*16 + j16] = init_c[jt*16 + j16];
    if (tid >= 256) {                              // stage xW[0] -> LDS
        int ti = tid - 256;
        int bb = ti >> 4, s = ti & 15;
        int gg = s & 3, j4 = (s >> 2) << 2;
        float4 v = *(const float4*)(xW + (size_t)bb*G4 + gg*512 + jt*16 + j4);
        float* dst = xwb + gg*256 + bb*16 + j4;
        dst[0]=v.x; dst[1]=v.y; dst[2]=v.z; dst[3]=v.w;
    }
    __syncthreads();

    for (int t = 0; t < T; ++t) {
        // ---- load h_t A-fragments ----
        const short8* hhi = (const short8*)(hbuf + (size_t)t*16384);
        const short8* hlo = hhi + 1024;
        short8 ah[8], al[8];
#pragma unroll
        for (int kt = 0; kt < 8; ++kt) {
            int c = ((khalf*8 + kt)*4 + quad)*16 + l15;
            ah[kt] = hhi[c];
            al[kt] = hlo[c];
        }
        // ---- split-bf16 MFMA ----
        float4v a0 = {0.f,0.f,0.f,0.f}, a1 = {0.f,0.f,0.f,0.f};
#pragma unroll
        for (int kt = 0; kt < 8; ++kt) {
            a0 = __builtin_amdgcn_mfma_f32_16x16x32_bf16(ah[kt], bh[kt], a0, 0, 0, 0);
            a1 = __builtin_amdgcn_mfma_f32_16x16x32_bf16(al[kt], bh[kt], a1, 0, 0, 0);
            a1 = __builtin_amdgcn_mfma_f32_16x16x32_bf16(ah[kt], bl[kt], a1, 0, 0, 0);
        }
        a0 += a1;
        *(float4v*)&part[(w*64 + lane)*4] = a0;    // D: m(b)=quad*4+reg, n(j)=lane&15
        __syncthreads();

        // ---- finalize: 256 threads = (b2, j16) ----
        if (tid < 256) {
            const int lsrc = ((b2 >> 2)*16 + j16)*4, r = b2 & 3;
            float gi = part[(0*256) + lsrc + r] + part[(1*256) + lsrc + r] + xwb[0*256 + b2*16 + j16];
            float gf = part[(2*256) + lsrc + r] + part[(3*256) + lsrc + r] + xwb[1*256 + b2*16 + j16];
            float gg = part[(4*256) + lsrc + r] + part[(5*256) + lsrc + r] + xwb[2*256 + b2*16 + j16];
            float go = part[(6*256) + lsrc + r] + part[(7*256) + lsrc + r] + xwb[3*256 + b2*16 + j16];
            float si = 1.f/(1.f+__expf(-gi));
            float sf = 1.f/(1.f+__expf(-gf));
            float so = 1.f/(1.f+__expf(-go));
            float cn = sf*cst[b2*16 + j16] + si*tanhf(gg);
            float hn = so*tanhf(cn);
            cst[b2*16 + j16] = cn;
            __builtin_nontemporal_store(hn, ys + (size_t)(t+1)*BS*H + b2*H + jt*16 + j16);
            const int k = jt*16 + j16;
            const int e = ((k >> 3)*16 + b2)*8 + (k & 7);
            unsigned short hi = bf16_rn(hn);
            unsigned short* hb1 = hbuf + (size_t)(t+1)*16384;
            hb1[e]        = hi;                       // plain; published by wbl2 in release
            hb1[8192 + e] = bf16_rn(hn - bf16_to_f(hi));
        }
        __syncthreads();   // per-wave vmcnt drain before barrier -> stores in L2

        if (t < T-1) {
            // arrival FIRST so its vmcnt(0) is clean (prefetch loads come after)
            if (tid == 0)
                __hip_atomic_store(&flags[jt*16], t+1, __ATOMIC_RELEASE, __HIP_MEMORY_SCOPE_AGENT);
            if (tid >= 256) {                       // stage xW[t+1] under the wait
                int ti = tid - 256;
                int bb = ti >> 4, s = ti & 15;
                int gg2 = s & 3, j4 = (s >> 2) << 2;
                float4 v = *(const float4*)(xW + (size_t)(t+1)*BS*G4 + bb*G4 + gg2*512 + jt*16 + j4);
                float* dst = xwb + gg2*256 + bb*16 + j4;
                dst[0]=v.x; dst[1]=v.y; dst[2]=v.z; dst[3]=v.w;
            }
            if (tid < 64) {                         // wave-parallel poll of 32 flags
                const int fidx = (tid & 31) << 4;
                int v;
                do {
                    v = __hip_atomic_load(&flags[fidx], __ATOMIC_RELAXED, __HIP_MEMORY_SCOPE_AGENT);
                } while (!__all(v >= t+1));
                __builtin_amdgcn_fence(__ATOMIC_ACQUIRE, "agent");  // one L1+L2 inv
            }
            __syncthreads();
        }
    }
}

// ---------------- fused attention: score[b,t,m] = sum_h tanh(af+q)*v ----------------
__global__ __launch_bounds__(256) void attn(const float* __restrict__ af,
                                            const float* __restrict__ q,
                                            const float* __restrict__ v,
                                            float* __restrict__ out)
{
    __shared__ float afs[64][68];
    __shared__ float qs[4][516];
    __shared__ float vs[512];
    const int tid = threadIdx.x;
    const int mc = blockIdx.x, tc = blockIdx.y, b = blockIdx.z;
    for (int i = tid; i < 4*128; i += 256) {
        int t = i >> 7, h4 = (i & 127) << 2;
        float4 x = *(const float4*)(q + ((size_t)((tc*4 + t)*16 + b) << 9) + h4);
        x.x *= K2C; x.y *= K2C; x.z *= K2C; x.w *= K2C;
        *(float4*)&qs[t][h4] = x;
    }
    for (int i = tid; i < 128; i += 256)
        *(float4*)&vs[i << 2] = *(const float4*)(v + (i << 2));
    const int ml = tid & 63, tg = tid >> 6;
    float acc = 0.f;
    for (int hc = 0; hc < 8; ++hc) {
        __syncthreads();
        for (int i = tid; i < 64*16; i += 256) {
            int m = i >> 4, h4 = (i & 15) << 2;
            float4 x = *(const float4*)(af + ((size_t)(b*NMEM + mc*64 + m) << 9) + hc*64 + h4);
            x.x *= K2C; x.y *= K2C; x.z *= K2C; x.w *= K2C;
            *(float4*)&afs[m][h4] = x;
        }
        __syncthreads();
#pragma unroll
        for (int h8 = 0; h8 < 8; ++h8) {
            float4 a0 = *(const float4*)&afs[ml][h8*8 + 0];
            float4 a1 = *(const float4*)&afs[ml][h8*8 + 4];
            float4 v0 = *(const float4*)&vs[hc*64 + h8*8 + 0];
            float4 v1 = *(const float4*)&vs[hc*64 + h8*8 + 4];
            float4 q0 = *(const float4*)&qs[tg][hc*64 + h8*8 + 0];
            float4 q1 = *(const float4*)&qs[tg][hc*64 + h8*8 + 4];
            const float* ap0 = (const float*)&a0; const float* ap1 = (const float*)&a1;
            const float* vp0 = (const float*)&v0; const float* vp1 = (const float*)&v1;
            const float* qp0 = (const float*)&q0; const float* qp1 = (const float*)&q1;
            float s = acc;
#pragma unroll
            for (int j = 0; j < 4; ++j) {
                float e = exp2f(ap0[j] + qp0[j]);
                s = fmaf(vp0[j], __builtin_amdgcn_rcpf(e + 1.f), s);
            }
#pragma unroll
            for (int j = 0; j < 4; ++j) {
                float e = exp2f(ap1[j] + qp1[j]);
                s = fmaf(vp1[j], __builtin_amdgcn_rcpf(e + 1.f), s);
            }
            acc = s;
        }
    }
    float Sv = 0.f;
    for (int i = 0; i < 512; i += 4) {
        float4 t4 = *(const float4*)&vs[i];
        Sv += t4.x + t4.y + t4.z + t4.w;
    }
    out[((size_t)b*T + tc*4 + tg)*NMEM + mc*64 + ml] = Sv - 2.f*acc;
}

extern "C" void kernel_launch(void* const* d_in, const int* in_sizes, int n_in,
                              void* d_out, int out_size, void* d_ws, size_t ws_size,
                              hipStream_t stream)
{
    const float* ks      = (const float*)d_in[0];
    const float* lstm_in = (const float*)d_in[2];
    const float* init_h  = (const float*)d_in[3];
    const float* init_c  = (const float*)d_in[4];
    const float* init_i  = (const float*)d_in[5];
    const float* w_ih    = (const float*)d_in[6];
    const float* w_hh    = (const float*)d_in[7];
    const float* b_ih    = (const float*)d_in[8];
    const float* b_hh    = (const float*)d_in[9];
    const float* wm      = (const float*)d_in[10];
    const float* wq      = (const float*)d_in[11];
    const float* av      = (const float*)d_in[12];

    float* ws   = (float*)d_ws;
    float* xW   = ws + OFF_XW;
    float* ys   = ws + OFF_YS;
    unsigned short* hbuf = (unsigned short*)(ws + OFF_HB);
    float* af   = ws + OFF_AF;
    float* qb   = ws + OFF_Q;
    float* xb   = ws + OFF_X;
    float* bias = ws + OFF_B;
    int*   flags= (int*)(ws + OFF_BAR);

    hipMemsetAsync(flags, 0, 512*sizeof(int), stream);

    const int prep_n = T*BS*D + G4 + 8192;
    prep<<<(prep_n + 255)/256, 256, 0, stream>>>(lstm_in, init_h, init_i,
                                                 b_ih, b_hh, xb, bias, hbuf);
    // xW[1024,2048] = x @ w_ih^T + bias   (split-bf16 MFMA)
    gemm_mfma<true><<<dim3(32, 16), 256, 0, stream>>>(xb, w_ih, xW, bias, G4, D);
    // LSTM recurrence (blocks 0-31) + af = ks @ wm (blocks 32-287)
    lstm_af<<<288, 512, 0, stream>>>(xW, w_hh, init_c, ks, wm, ys, hbuf, af, flags);
    // qb[1024,512] = ys[1..64] @ wq       (split-bf16 MFMA)
    gemm_mfma<false><<<dim3(8, 16), 256, 0, stream>>>(ys + BS*H, wq, qb, nullptr, H, H);
    attn<<<dim3(4, 16, 16), 256, 0, stream>>>(af, qb, av, (float*)d_out);
}

// Round 2
// 424.208 us; speedup vs baseline: 1.0919x; 1.0919x over previous
//
#include <hip/hip_runtime.h>

#define BS   16
#define NMEM 256
#define NQ   63
#define T    64          // NQ + 1
#define D    512
#define H    512
#define G4   2048        // 4*H

#define K2C  2.885390081777927f   // 2*log2(e)

typedef __attribute__((ext_vector_type(8))) short short8;
typedef __attribute__((ext_vector_type(4))) float float4v;

// ---------------- workspace layout (float offsets) ----------------
enum : size_t {
    OFF_XW  = 0,                            // [T][BS][G4]
    OFF_YS  = OFF_XW  + (size_t)T*BS*G4,    // [T+1][BS][H]  (fp32, b-major, for q-gemm)
    OFF_HB  = OFF_YS  + (size_t)(T+1)*BS*H, // [T+1][2][8192] bf16 hi/lo
    OFF_AF  = OFF_HB  + (size_t)(T+1)*BS*H, // [BS][NMEM][H]
    OFF_Q   = OFF_AF  + (size_t)BS*NMEM*H,  // [T][BS][H]
    OFF_X   = OFF_Q   + (size_t)T*BS*H,     // [T][BS][D]
    OFF_B   = OFF_X   + (size_t)T*BS*D,     // [G4]
    OFF_BAR = OFF_B   + (size_t)G4,         // 512 ints: 32 flags, stride 16
};

__device__ inline unsigned short bf16_rn(float x) {
    union { float f; unsigned u; } a; a.f = x;
    unsigned r = a.u + 0x7FFFu + ((a.u >> 16) & 1u);
    return (unsigned short)(r >> 16);
}
__device__ inline float bf16_to_f(unsigned short s) {
    union { float f; unsigned u; } a; a.u = ((unsigned)s) << 16;
    return a.f;
}

// ---------------- prep: build x, bias, hbuf[0] ----------------
__global__ void prep(const float* __restrict__ lstm_in, const float* __restrict__ init_h,
                     const float* __restrict__ init_i,
                     const float* __restrict__ b_ih, const float* __restrict__ b_hh,
                     float* __restrict__ xbuf, float* __restrict__ biasbuf,
                     unsigned short* __restrict__ hb0)
{
    int i = blockIdx.x * blockDim.x + threadIdx.x;
    const int NX = T*BS*D;
    if (i < NX) {
        int d = i & 511; int r = i >> 9; int t = r >> 4; int b = r & 15;
        float v = (t == 0) ? init_i[d] : lstm_in[((size_t)(b*NQ) + (t-1))*D + d];
        __builtin_nontemporal_store(v, xbuf + i);
    } else if (i < NX + G4) {
        int j = i - NX; biasbuf[j] = b_ih[j] + b_hh[j];
    } else if (i < NX + G4 + 8192) {
        int e = i - (NX + G4);
        int iw = e & 7;
        int k = ((e >> 3) >> 4) * 8 + iw;
        float h0 = init_h[k];
        unsigned short hi = bf16_rn(h0);
        unsigned short lo = bf16_rn(h0 - bf16_to_f(hi));
        hb0[e] = hi;
        hb0[8192 + e] = lo;
    }
}

// ---------------- split-bf16 MFMA GEMM unit ----------------
// 256 threads compute a 64x64 C tile of A[M,K] @ op(B), fp32 in/out.
// BT=true: B is [N,K] (C = A*B^T). BT=false: B is [K,N].
// C = Ah*Bh + Al*Bh + Ah*Bl (split-bf16, ~2^-16 relative).
template<bool BT>
__device__ inline void gemm_unit(const float* __restrict__ A, const float* __restrict__ B,
                                 float* __restrict__ C, const float* __restrict__ bias,
                                 int N, int K, int tm, int tn, int t2)
{
    const int w = t2 >> 6, lane = t2 & 63;
    const int quad = lane >> 4, l15 = lane & 15;
    const int am = tm + w*16 + l15;
    float4v acch[4] = {{0,0,0,0},{0,0,0,0},{0,0,0,0},{0,0,0,0}};
    float4v accl[4] = {{0,0,0,0},{0,0,0,0},{0,0,0,0},{0,0,0,0}};
    for (int k0 = 0; k0 < K; k0 += 32) {
        const float* ap = A + (size_t)am*K + k0 + quad*8;
        float4 a0 = *(const float4*)ap, a1 = *(const float4*)(ap+4);
        float av[8] = {a0.x,a0.y,a0.z,a0.w,a1.x,a1.y,a1.z,a1.w};
        short8 ah, al;
#pragma unroll
        for (int i = 0; i < 8; ++i) {
            unsigned short hi = bf16_rn(av[i]);
            ah[i] = (short)hi; al[i] = (short)bf16_rn(av[i] - bf16_to_f(hi));
        }
#pragma unroll
        for (int ni = 0; ni < 4; ++ni) {
            const int n = tn + ni*16 + l15;
            float bv[8];
            if (BT) {
                const float* bp = B + (size_t)n*K + k0 + quad*8;
                float4 b0 = *(const float4*)bp, b1 = *(const float4*)(bp+4);
                bv[0]=b0.x; bv[1]=b0.y; bv[2]=b0.z; bv[3]=b0.w;
                bv[4]=b1.x; bv[5]=b1.y; bv[6]=b1.z; bv[7]=b1.w;
            } else {
                const float* bp = B + (size_t)(k0 + quad*8)*N + n;
#pragma unroll
                for (int i = 0; i < 8; ++i) bv[i] = bp[(size_t)i*N];
            }
            short8 bh, bl;
#pragma unroll
            for (int i = 0; i < 8; ++i) {
                unsigned short hi = bf16_rn(bv[i]);
                bh[i] = (short)hi; bl[i] = (short)bf16_rn(bv[i] - bf16_to_f(hi));
            }
            acch[ni] = __builtin_amdgcn_mfma_f32_16x16x32_bf16(ah, bh, acch[ni], 0, 0, 0);
            accl[ni] = __builtin_amdgcn_mfma_f32_16x16x32_bf16(al, bh, accl[ni], 0, 0, 0);
            accl[ni] = __builtin_amdgcn_mfma_f32_16x16x32_bf16(ah, bl, accl[ni], 0, 0, 0);
        }
    }
#pragma unroll
    for (int ni = 0; ni < 4; ++ni) {
        const int n = tn + ni*16 + l15;
        float bb = bias ? bias[n] : 0.f;
        float4v r = acch[ni] + accl[ni];
#pragma unroll
        for (int j = 0; j < 4; ++j) {
            int row = tm + w*16 + quad*4 + j;
            __builtin_nontemporal_store(r[j] + bb, C + (size_t)row*N + n);
        }
    }
}

template<bool BT>
__global__ __launch_bounds__(256) void gemm_mfma(const float* __restrict__ A,
                                                 const float* __restrict__ B,
                                                 float* __restrict__ C,
                                                 const float* __restrict__ bias,
                                                 int N, int K)
{
    gemm_unit<BT>(A, B, C, bias, N, K, blockIdx.y*64, blockIdx.x*64, threadIdx.x);
}

// ---------------- persistent LSTM (blocks 0-31) + fused af GEMM (blocks 32-287) ----
// lstm: block jt owns hidden j-tile of 16 x 4 gates; 8 waves = (gate, k-half);
// weights as bf16 hi/lo B-fragments in VGPRs.
// barrier v5: ALL cross-block payload (h hi/lo, flags) moves via sc0 sc1
// cache-bypass loads/stores through IF$ -> no buffer_wbl2 / buffer_inv per step.
// af: blocks 32-287 each run two independent 64x64 gemm_unit tiles of ks@wm.
__global__ __launch_bounds__(512, 2) void lstm_af(
    const float* __restrict__ xW,        // [T][BS][G4]
    const float* __restrict__ w_hh,      // [G4][H]
    const float* __restrict__ init_c,    // [H]
    const float* __restrict__ ks,        // [BS*NMEM][D]
    const float* __restrict__ wm,        // [D][H]
    float* __restrict__ ys,              // [T+1][BS][H]
    unsigned short* __restrict__ hbuf,   // [T+1][2][8192]
    float* __restrict__ af,              // [BS*NMEM][H]
    int* __restrict__ flags)             // 32 flags, stride 16 ints
{
    const int tid = threadIdx.x;

    if (blockIdx.x >= 32) {
        // ---------- fused af = ks @ wm (split-bf16 MFMA, no LDS, no barriers) ------
        const int u = tid >> 8;                    // two 256-thr units per block
        const int tau = (blockIdx.x - 32)*2 + u;   // 0..511 tiles: M=4096/64 x N=512/64
        gemm_unit<false>(ks, wm, af, nullptr, H, D, (tau >> 3)*64, (tau & 7)*64, tid & 255);
        return;
    }

    // ---------- LSTM recurrence ----------
    __shared__ float smem[3328];
    float* part = smem;              // [8][64][4]
    float* cst  = smem + 2048;       // [16][16]
    float* xwb  = smem + 2304;       // [4][16][16]  (gate, b, j16) staged xW[t]

    const int jt    = blockIdx.x;
    const int w     = tid >> 6;
    const int g     = w >> 1;
    const int khalf = w & 1;
    const int lane  = tid & 63;
    const int quad  = lane >> 4;
    const int l15   = lane & 15;

    // one-time weight preload -> bf16 hi/lo B-fragments in VGPRs
    short8 bh[8], bl[8];
    {
        const int row = g*512 + jt*16 + l15;
        const float* wr = w_hh + (size_t)row*H + khalf*256 + quad*8;
#pragma unroll
        for (int kt = 0; kt < 8; ++kt) {
            const float* wp = wr + kt*32;
#pragma unroll
            for (int i = 0; i < 8; ++i) {
                float v = wp[i];
                unsigned short hi = bf16_rn(v);
                bh[kt][i] = (short)hi;
                bl[kt][i] = (short)bf16_rn(v - bf16_to_f(hi));
            }
        }
    }

    const int b2 = tid >> 4, j16 = tid & 15;       // finalize mapping (tid<256)
    if (tid < 256) cst[b2*16 + j16] = init_c[jt*16 + j16];
    if (tid >= 256) {                              // stage xW[0] -> LDS
        int ti = tid - 256;
        int bb = ti >> 4, s = ti & 15;
        int gg = s & 3, j4 = (s >> 2) << 2;
        float4 v = *(const float4*)(xW + (size_t)bb*G4 + gg*512 + jt*16 + j4);
        float* dst = xwb + gg*256 + bb*16 + j4;
        dst[0]=v.x; dst[1]=v.y; dst[2]=v.z; dst[3]=v.w;
    }
    __syncthreads();

    for (int t = 0; t < T; ++t) {
        // ---- load h_t A-fragments: cache-bypass (sc0 sc1) straight from IF$ ----
        const unsigned short* hbt = hbuf + (size_t)t*16384;
        short8 ah[8], al[8];
#pragma unroll
        for (int kt = 0; kt < 8; ++kt) {
            int c = ((khalf*8 + kt)*4 + quad)*16 + l15;
            const unsigned short* p0 = hbt + (size_t)c*8;
            const unsigned short* p1 = p0 + 8192;
            asm volatile("global_load_dwordx4 %0, %1, off sc0 sc1"
                         : "=v"(ah[kt]) : "v"(p0) : "memory");
            asm volatile("global_load_dwordx4 %0, %1, off sc0 sc1"
                         : "=v"(al[kt]) : "v"(p1) : "memory");
        }
        asm volatile("s_waitcnt vmcnt(0)" ::: "memory");
        __builtin_amdgcn_sched_barrier(0);   // keep MFMAs below the waitcnt (rule #18)

        // ---- split-bf16 MFMA ----
        float4v a0 = {0.f,0.f,0.f,0.f}, a1 = {0.f,0.f,0.f,0.f};
#pragma unroll
        for (int kt = 0; kt < 8; ++kt) {
            a0 = __builtin_amdgcn_mfma_f32_16x16x32_bf16(ah[kt], bh[kt], a0, 0, 0, 0);
            a1 = __builtin_amdgcn_mfma_f32_16x16x32_bf16(al[kt], bh[kt], a1, 0, 0, 0);
            a1 = __builtin_amdgcn_mfma_f32_16x16x32_bf16(ah[kt], bl[kt], a1, 0, 0, 0);
        }
        a0 += a1;
        *(float4v*)&part[(w*64 + lane)*4] = a0;    // D: m(b)=quad*4+reg, n(j)=lane&15
        __syncthreads();

        // ---- finalize: 256 threads = (b2, j16) ----
        if (tid < 256) {
            const int lsrc = ((b2 >> 2)*16 + j16)*4, r = b2 & 3;
            float gi = part[(0*256) + lsrc + r] + part[(1*256) + lsrc + r] + xwb[0*256 + b2*16 + j16];
            float gf = part[(2*256) + lsrc + r] + part[(3*256) + lsrc + r] + xwb[1*256 + b2*16 + j16];
            float gg = part[(4*256) + lsrc + r] + part[(5*256) + lsrc + r] + xwb[2*256 + b2*16 + j16];
            float go = part[(6*256) + lsrc + r] + part[(7*256) + lsrc + r] + xwb[3*256 + b2*16 + j16];
            float si = 1.f/(1.f+__expf(-gi));
            float sf = 1.f/(1.f+__expf(-gf));
            float so = 1.f/(1.f+__expf(-go));
            float cn = sf*cst[b2*16 + j16] + si*tanhf(gg);
            float hn = so*tanhf(cn);
            cst[b2*16 + j16] = cn;
            __builtin_nontemporal_store(hn, ys + (size_t)(t+1)*BS*H + b2*H + jt*16 + j16);
            const int k = jt*16 + j16;
            const int e = ((k >> 3)*16 + b2)*8 + (k & 7);
            unsigned short hi = bf16_rn(hn);
            unsigned int hv = (unsigned int)hi;
            unsigned int lv = (unsigned int)bf16_rn(hn - bf16_to_f(hi));
            unsigned short* hb1 = hbuf + (size_t)(t+1)*16384;
            // write-through to IF$ (bypass L1+L2): globally visible once vmcnt-acked
            asm volatile("global_store_short %0, %1, off sc0 sc1"
                         :: "v"(hb1 + e), "v"(hv) : "memory");
            asm volatile("global_store_short %0, %1, off sc0 sc1"
                         :: "v"(hb1 + 8192 + e), "v"(lv) : "memory");
            // drain own stores (inline-asm stores are untracked by the compiler's
            // barrier lowering) so the post-barrier flag store orders after payload
            asm volatile("s_waitcnt vmcnt(0)" ::: "memory");
        }
        __syncthreads();

        if (t < T-1) {
            // arrival: payload of ALL waves acked at IF$ (per-wave drain + barrier)
            if (tid == 0) {
                int fv = t + 1;
                asm volatile("global_store_dword %0, %1, off sc0 sc1"
                             :: "v"(flags + jt*16), "v"(fv) : "memory");
            }
            if (tid >= 256) {                       // stage xW[t+1] under the wait
                int ti = tid - 256;
                int bb = ti >> 4, s = ti & 15;
                int gg2 = s & 3, j4 = (s >> 2) << 2;
                float4 v = *(const float4*)(xW + (size_t)(t+1)*BS*G4 + bb*G4 + gg2*512 + jt*16 + j4);
                float* dst = xwb + gg2*256 + bb*16 + j4;
                dst[0]=v.x; dst[1]=v.y; dst[2]=v.z; dst[3]=v.w;
            }
            if (tid < 64) {                         // wave-parallel poll of 32 flags
                const int fidx = (tid & 31) << 4;
                const int* fp = flags + fidx;
                int v;
                do {
                    asm volatile("global_load_dword %0, %1, off sc0 sc1\n\t"
                                 "s_waitcnt vmcnt(0)"
                                 : "=v"(v) : "v"(fp) : "memory");
                } while (!__all(v >= t+1));
            }
            __syncthreads();
        }
    }
}

// ---------------- fused attention: score[b,t,m] = sum_h tanh(af+q)*v ----------------
__global__ __launch_bounds__(256) void attn(const float* __restrict__ af,
                                            const float* __restrict__ q,
                                            const float* __restrict__ v,
                                            float* __restrict__ out)
{
    __shared__ float afs[64][68];
    __shared__ float qs[4][516];
    __shared__ float vs[512];
    const int tid = threadIdx.x;
    const int mc = blockIdx.x, tc = blockIdx.y, b = blockIdx.z;
    for (int i = tid; i < 4*128; i += 256) {
        int t = i >> 7, h4 = (i & 127) << 2;
        float4 x = *(const float4*)(q + ((size_t)((tc*4 + t)*16 + b) << 9) + h4);
        x.x *= K2C; x.y *= K2C; x.z *= K2C; x.w *= K2C;
        *(float4*)&qs[t][h4] = x;
    }
    for (int i = tid; i < 128; i += 256)
        *(float4*)&vs[i << 2] = *(const float4*)(v + (i << 2));
    const int ml = tid & 63, tg = tid >> 6;
    float acc = 0.f;
    for (int hc = 0; hc < 8; ++hc) {
        __syncthreads();
        for (int i = tid; i < 64*16; i += 256) {
            int m = i >> 4, h4 = (i & 15) << 2;
            float4 x = *(const float4*)(af + ((size_t)(b*NMEM + mc*64 + m) << 9) + hc*64 + h4);
            x.x *= K2C; x.y *= K2C; x.z *= K2C; x.w *= K2C;
            *(float4*)&afs[m][h4] = x;
        }
        __syncthreads();
#pragma unroll
        for (int h8 = 0; h8 < 8; ++h8) {
            float4 a0 = *(const float4*)&afs[ml][h8*8 + 0];
            float4 a1 = *(const float4*)&afs[ml][h8*8 + 4];
            float4 v0 = *(const float4*)&vs[hc*64 + h8*8 + 0];
            float4 v1 = *(const float4*)&vs[hc*64 + h8*8 + 4];
            float4 q0 = *(const float4*)&qs[tg][hc*64 + h8*8 + 0];
            float4 q1 = *(const float4*)&qs[tg][hc*64 + h8*8 + 4];
            const float* ap0 = (const float*)&a0; const float* ap1 = (const float*)&a1;
            const float* vp0 = (const float*)&v0; const float* vp1 = (const float*)&v1;
            const float* qp0 = (const float*)&q0; const float* qp1 = (const float*)&q1;
            float s = acc;
#pragma unroll
            for (int j = 0; j < 4; ++j) {
                float e = exp2f(ap0[j] + qp0[j]);
                s = fmaf(vp0[j], __builtin_amdgcn_rcpf(e + 1.f), s);
            }
#pragma unroll
            for (int j = 0; j < 4; ++j) {
                float e = exp2f(ap1[j] + qp1[j]);
                s = fmaf(vp1[j], __builtin_amdgcn_rcpf(e + 1.f), s);
            }
            acc = s;
        }
    }
    float Sv = 0.f;
    for (int i = 0; i < 512; i += 4) {
        float4 t4 = *(const float4*)&vs[i];
        Sv += t4.x + t4.y + t4.z + t4.w;
    }
    out[((size_t)b*T + tc*4 + tg)*NMEM + mc*64 + ml] = Sv - 2.f*acc;
}

extern "C" void kernel_launch(void* const* d_in, const int* in_sizes, int n_in,
                              void* d_out, int out_size, void* d_ws, size_t ws_size,
                              hipStream_t stream)
{
    const float* ks      = (const float*)d_in[0];
    const float* lstm_in = (const float*)d_in[2];
    const float* init_h  = (const float*)d_in[3];
    const float* init_c  = (const float*)d_in[4];
    const float* init_i  = (const float*)d_in[5];
    const float* w_ih    = (const float*)d_in[6];
    const float* w_hh    = (const float*)d_in[7];
    const float* b_ih    = (const float*)d_in[8];
    const float* b_hh    = (const float*)d_in[9];
    const float* wm      = (const float*)d_in[10];
    const float* wq      = (const float*)d_in[11];
    const float* av      = (const float*)d_in[12];

    float* ws   = (float*)d_ws;
    float* xW   = ws + OFF_XW;
    float* ys   = ws + OFF_YS;
    unsigned short* hbuf = (unsigned short*)(ws + OFF_HB);
    float* af   = ws + OFF_AF;
    float* qb   = ws + OFF_Q;
    float* xb   = ws + OFF_X;
    float* bias = ws + OFF_B;
    int*   flags= (int*)(ws + OFF_BAR);

    hipMemsetAsync(flags, 0, 512*sizeof(int), stream);

    const int prep_n = T*BS*D + G4 + 8192;
    prep<<<(prep_n + 255)/256, 256, 0, stream>>>(lstm_in, init_h, init_i,
                                                 b_ih, b_hh, xb, bias, hbuf);
    // xW[1024,2048] = x @ w_ih^T + bias   (split-bf16 MFMA)
    gemm_mfma<true><<<dim3(32, 16), 256, 0, stream>>>(xb, w_ih, xW, bias, G4, D);
    // LSTM recurrence (blocks 0-31) + af = ks @ wm (blocks 32-287)
    lstm_af<<<288, 512, 0, stream>>>(xW, w_hh, init_c, ks, wm, ys, hbuf, af, flags);
    // qb[1024,512] = ys[1..64] @ wq       (split-bf16 MFMA)
    gemm_mfma<false><<<dim3(8, 16), 256, 0, stream>>>(ys + BS*H, wq, qb, nullptr, H, H);
    attn<<<dim3(4, 16, 16), 256, 0, stream>>>(af, qb, av, (float*)d_out);
}